// Round 1
// baseline (263.601 us; speedup 1.0000x reference)
//
#include <hip/hip_runtime.h>
#include <hip/hip_bf16.h>

#define BN 8192      // batch rows
#define MM 8199      // real rows (BN + 7 centers)
#define MP 8208      // padded to multiple of 16
#define HH 128       // feature dim
#define EE 256       // center embedding dim
#define NTILE 513    // MP / 16 j-tiles
#define JCHUNKS 64   // j-chunks (grid.y * 4 waves)
#define NUM_HIST 7

typedef __attribute__((ext_vector_type(8))) short short8;   // 8 bf16 = 4 VGPRs
typedef __attribute__((ext_vector_type(4))) float floatx4;

// ---- kernel A: curr_centers[c][h] = sum_e centers[c][e]*fc_w[h][e] + fc_b[h]
// 4 waves/block, one output per wave.
__global__ __launch_bounds__(256)
void centers_kernel(const float* __restrict__ centers,
                    const float* __restrict__ fc_w,
                    const float* __restrict__ fc_b,
                    float* __restrict__ curr) {
  int wid = threadIdx.x >> 6, lane = threadIdx.x & 63;
  int o = (blockIdx.x << 2) | wid;       // 0..895 = c*128 + h
  int c = o >> 7, h = o & 127;
  const float4* ce = (const float4*)(centers + c * EE);
  const float4* w  = (const float4*)(fc_w + h * EE);
  float4 a = ce[lane];
  float4 b = w[lane];
  float s = a.x * b.x + a.y * b.y + a.z * b.z + a.w * b.w;
#pragma unroll
  for (int m = 1; m < 64; m <<= 1) s += __shfl_xor(s, m);
  if (lane == 0) curr[o] = s + fc_b[h];
}

// ---- kernel B: rn[r] = bf16( all_reps[r] / max(||all_reps[r]||, 1e-8) ), labels_pad
// 4 waves/block, one row per wave.
__global__ __launch_bounds__(256)
void norm_kernel(const float* __restrict__ reps,
                 const float* __restrict__ curr,
                 const int* __restrict__ labels,
                 __hip_bfloat16* __restrict__ rn,
                 int* __restrict__ labp) {
  int wid = threadIdx.x >> 6, lane = threadIdx.x & 63;
  int r = (blockIdx.x << 2) | wid;       // 0..MP-1
  float2 v = make_float2(0.f, 0.f);
  if (r < BN)      v = ((const float2*)(reps + (size_t)r * HH))[lane];
  else if (r < MM) v = ((const float2*)(curr + (size_t)(r - BN) * HH))[lane];
  float ss = v.x * v.x + v.y * v.y;
#pragma unroll
  for (int m = 1; m < 64; m <<= 1) ss += __shfl_xor(ss, m);
  float inv = 1.0f / fmaxf(sqrtf(ss), 1e-8f);
  __hip_bfloat162 h2;
  h2.x = __float2bfloat16(v.x * inv);
  h2.y = __float2bfloat16(v.y * inv);
  ((__hip_bfloat162*)(rn + (size_t)r * HH))[lane] = h2;
  if (lane == 0) labp[r] = (r < BN) ? labels[r] : (r < MM ? r - BN : -1);
}

// ---- kernel C: per i-row, tot_i = sum_j e_ij (j!=i), pos_i = same over label match
// e_ij = exp2((cos_ij - 1) * (0.5/TEMP) * log2e)   [global-max shift cancels in ratio]
// Padded j-columns (rn==0) contribute exactly exp2f(-K2) each to tot; the loss
// kernel subtracts the exact constant 9*exp2f(-K2). Padded labp=-1 never matches.
// 4 waves/block, each wave owns j-chunk = blockIdx.y*4 + wid (64 chunks total).
__global__ __launch_bounds__(256, 5)
void main_kernel(const __hip_bfloat16* __restrict__ rn,
                 const int* __restrict__ labp,
                 float* __restrict__ tot,
                 float* __restrict__ pos) {
  const int lane = threadIdx.x & 63;
  const int wid  = threadIdx.x >> 6;
  const int q = lane >> 4, col = lane & 15;
  const int ibase = blockIdx.x * 64;
  const int chunk = (blockIdx.y << 2) | wid;   // 0..63
  const short* rns = (const short*)rn;

  // A fragments: lane holds A[m=col][k = kk*32 + q*8 + 0..7]
  short8 afrag[4][4];
#pragma unroll
  for (int it = 0; it < 4; ++it) {
    const short8* p = (const short8*)(rns + (size_t)(ibase + it * 16 + col) * HH + q * 8);
    afrag[it][0] = p[0];
    afrag[it][1] = p[4];
    afrag[it][2] = p[8];
    afrag[it][3] = p[12];
  }
  // i-labels for C/D layout rows: row = q*4 + r
  int labi[4][4];
#pragma unroll
  for (int it = 0; it < 4; ++it)
#pragma unroll
    for (int r = 0; r < 4; ++r)
      labi[it][r] = labp[ibase + it * 16 + q * 4 + r];

  float stot[4][4] = {};
  float spos[4][4] = {};
  const float K2 = 10.30496147f;  // 0.5/0.07 * log2(e)

  // pointer-increment B addressing: chunk strides 64 tiles = 1024 rows
  const short* bptr = rns + (chunk * 16 + col) * HH + q * 8;
  const int* lptr = labp + chunk * 16 + col;

  for (int jb = chunk * 16; jb < MP; jb += 16 * JCHUNKS) {
    // B fragments: lane holds B[k = kk*32 + q*8 + 0..7][n=col] = rn[jb+col][k]
    short8 b0 = ((const short8*)bptr)[0];
    short8 b1 = ((const short8*)bptr)[4];
    short8 b2 = ((const short8*)bptr)[8];
    short8 b3 = ((const short8*)bptr)[12];
    const int labj = *lptr;
    bptr += 16 * JCHUNKS * HH;
    lptr += 16 * JCHUNKS;
#pragma unroll
    for (int it = 0; it < 4; ++it) {
      floatx4 acc = {0.f, 0.f, 0.f, 0.f};
      acc = __builtin_amdgcn_mfma_f32_16x16x32_bf16(afrag[it][0], b0, acc, 0, 0, 0);
      acc = __builtin_amdgcn_mfma_f32_16x16x32_bf16(afrag[it][1], b1, acc, 0, 0, 0);
      acc = __builtin_amdgcn_mfma_f32_16x16x32_bf16(afrag[it][2], b2, acc, 0, 0, 0);
      acc = __builtin_amdgcn_mfma_f32_16x16x32_bf16(afrag[it][3], b3, acc, 0, 0, 0);
      const bool isdiag = (jb == ibase + it * 16);  // wave-uniform
#pragma unroll
      for (int r = 0; r < 4; ++r) {
        // C/D layout: row = q*4 + r, col = lane&15 → i = ibase+it*16+q*4+r, j = jb+col
        float e = exp2f(fmaf(acc[r], K2, -K2));
        if (isdiag && (col == q * 4 + r)) e = 0.f;   // exclude diagonal j==i
        stot[it][r] += e;
        spos[it][r] += (labj == labi[it][r]) ? e : 0.f;
      }
    }
  }

  // reduce across the 16 column-lanes (xor over low 4 lane bits)
#pragma unroll
  for (int it = 0; it < 4; ++it)
#pragma unroll
    for (int r = 0; r < 4; ++r) {
      float tt = stot[it][r], pp = spos[it][r];
#pragma unroll
      for (int m = 1; m <= 8; m <<= 1) {
        tt += __shfl_xor(tt, m);
        pp += __shfl_xor(pp, m);
      }
      if (col == 0) {
        int i = ibase + it * 16 + q * 4 + r;
        atomicAdd(&tot[i], tt);
        atomicAdd(&pos[i], pp);
      }
    }
}

// ---- kernel D: loss = sum(lv * (lv>0.3)) / (sum(lv>0.3) + eps),
//      lv = -log( ((pos/(tot-9*epad))/(hist[lab]+eps)) + eps )
__global__ __launch_bounds__(1024)
void loss_kernel(const float* __restrict__ tot,
                 const float* __restrict__ pos,
                 const int* __restrict__ labels,
                 float* __restrict__ out) {
  __shared__ int hist[NUM_HIST];
  __shared__ float s1[16], s2[16];
  const int tid = threadIdx.x;
  const int lane = tid & 63, wid = tid >> 6;
  if (tid < NUM_HIST) hist[tid] = 0;
  __syncthreads();
  // ballot-based histogram: 7 ballots per 1024-element stripe, no LDS contention
  int cnt0 = 0, cnt1 = 0, cnt2 = 0, cnt3 = 0, cnt4 = 0, cnt5 = 0, cnt6 = 0;
  for (int i = tid; i < BN; i += 1024) {
    int lab = labels[i];
    unsigned long long m0 = __ballot(lab == 0);
    unsigned long long m1 = __ballot(lab == 1);
    unsigned long long m2 = __ballot(lab == 2);
    unsigned long long m3 = __ballot(lab == 3);
    unsigned long long m4 = __ballot(lab == 4);
    unsigned long long m5 = __ballot(lab == 5);
    unsigned long long m6 = __ballot(lab == 6);
    if (lane == 0) {
      cnt0 += __popcll(m0); cnt1 += __popcll(m1); cnt2 += __popcll(m2);
      cnt3 += __popcll(m3); cnt4 += __popcll(m4); cnt5 += __popcll(m5);
      cnt6 += __popcll(m6);
    }
  }
  if (lane == 0) {
    atomicAdd(&hist[0], cnt0); atomicAdd(&hist[1], cnt1);
    atomicAdd(&hist[2], cnt2); atomicAdd(&hist[3], cnt3);
    atomicAdd(&hist[4], cnt4); atomicAdd(&hist[5], cnt5);
    atomicAdd(&hist[6], cnt6);
  }
  __syncthreads();
  const float K2 = 10.30496147f;
  const float epad = exp2f(-K2);     // exact value each padded column added to tot
  float lsum = 0.f, msum = 0.f;
  for (int i = tid; i < BN; i += 1024) {
    float t = tot[i] - 9.0f * epad;
    float p = pos[i];
    float c = (float)hist[labels[i]];   // = sum(pos_mask*mask) exactly
    float pr = (p / t) / (c + 1e-8f);
    float lv = -logf(pr + 1e-8f);
    if (lv > 0.3f) { lsum += lv; msum += 1.f; }
  }
#pragma unroll
  for (int m = 1; m < 64; m <<= 1) {
    lsum += __shfl_xor(lsum, m);
    msum += __shfl_xor(msum, m);
  }
  if (lane == 0) { s1[wid] = lsum; s2[wid] = msum; }
  __syncthreads();
  if (wid == 0) {
    float a = (lane < 16) ? s1[lane] : 0.f;
    float b = (lane < 16) ? s2[lane] : 0.f;
#pragma unroll
    for (int m = 1; m < 16; m <<= 1) {
      a += __shfl_xor(a, m);
      b += __shfl_xor(b, m);
    }
    if (lane == 0) out[0] = a / (b + 1e-8f);
  }
}

extern "C" void kernel_launch(void* const* d_in, const int* in_sizes, int n_in,
                              void* d_out, int out_size, void* d_ws, size_t ws_size,
                              hipStream_t stream) {
  const float* reps    = (const float*)d_in[0];  // [8192,128]
  const int*   labels  = (const int*)d_in[1];    // [8192]
  const float* centers = (const float*)d_in[2];  // [7,256]
  const float* fc_w    = (const float*)d_in[3];  // [128,256]
  const float* fc_b    = (const float*)d_in[4];  // [128]
  float* out = (float*)d_out;

  char* ws = (char*)d_ws;
  float* curr = (float*)ws;                              // 7*128*4   = 3584 B
  int* labp   = (int*)(ws + 4096);                       // 8208*4    = 32832 B
  __hip_bfloat16* rn = (__hip_bfloat16*)(ws + 40960);    // 8208*128*2 = 2101248 B
  float* tot = (float*)(ws + 40960 + 2101248);           // 8192*4
  float* pos = tot + BN;                                 // 8192*4

  hipMemsetAsync(tot, 0, 2 * BN * sizeof(float), stream);
  centers_kernel<<<224, 256, 0, stream>>>(centers, fc_w, fc_b, curr);
  norm_kernel<<<2052, 256, 0, stream>>>(reps, curr, labels, rn, labp);
  main_kernel<<<dim3(128, 16), 256, 0, stream>>>(rn, labp, tot, pos);
  loss_kernel<<<1, 1024, 0, stream>>>(tot, pos, labels, out);
}

// Round 2
// 138.154 us; speedup vs baseline: 1.9080x; 1.9080x over previous
//
#include <hip/hip_runtime.h>
#include <hip/hip_bf16.h>

#define BN 8192      // batch rows
#define MM 8199      // real rows (BN + 7 centers)
#define MP 8208      // padded to multiple of 16
#define HH 128       // feature dim
#define EE 256       // center embedding dim
#define NTILE 513    // MP / 16 j-tiles
#define JCHUNKS 64   // j-chunks (grid.y * 4 waves)
#define NUM_HIST 7

typedef __attribute__((ext_vector_type(8))) short short8;   // 8 bf16 = 4 VGPRs
typedef __attribute__((ext_vector_type(4))) float floatx4;

// ---- kernel A: curr_centers[c][h] = sum_e centers[c][e]*fc_w[h][e] + fc_b[h]
// 4 waves/block, one output per wave.
__global__ __launch_bounds__(256)
void centers_kernel(const float* __restrict__ centers,
                    const float* __restrict__ fc_w,
                    const float* __restrict__ fc_b,
                    float* __restrict__ curr) {
  int wid = threadIdx.x >> 6, lane = threadIdx.x & 63;
  int o = (blockIdx.x << 2) | wid;       // 0..895 = c*128 + h
  int c = o >> 7, h = o & 127;
  const float4* ce = (const float4*)(centers + c * EE);
  const float4* w  = (const float4*)(fc_w + h * EE);
  float4 a = ce[lane];
  float4 b = w[lane];
  float s = a.x * b.x + a.y * b.y + a.z * b.z + a.w * b.w;
#pragma unroll
  for (int m = 1; m < 64; m <<= 1) s += __shfl_xor(s, m);
  if (lane == 0) curr[o] = s + fc_b[h];
}

// ---- kernel B: rn[r] = bf16( all_reps[r] / max(||all_reps[r]||, 1e-8) ), labels_pad
// 4 waves/block, one row per wave.
__global__ __launch_bounds__(256)
void norm_kernel(const float* __restrict__ reps,
                 const float* __restrict__ curr,
                 const int* __restrict__ labels,
                 __hip_bfloat16* __restrict__ rn,
                 int* __restrict__ labp) {
  int wid = threadIdx.x >> 6, lane = threadIdx.x & 63;
  int r = (blockIdx.x << 2) | wid;       // 0..MP-1
  float2 v = make_float2(0.f, 0.f);
  if (r < BN)      v = ((const float2*)(reps + (size_t)r * HH))[lane];
  else if (r < MM) v = ((const float2*)(curr + (size_t)(r - BN) * HH))[lane];
  float ss = v.x * v.x + v.y * v.y;
#pragma unroll
  for (int m = 1; m < 64; m <<= 1) ss += __shfl_xor(ss, m);
  float inv = 1.0f / fmaxf(sqrtf(ss), 1e-8f);
  __hip_bfloat162 h2;
  h2.x = __float2bfloat16(v.x * inv);
  h2.y = __float2bfloat16(v.y * inv);
  ((__hip_bfloat162*)(rn + (size_t)r * HH))[lane] = h2;
  if (lane == 0) labp[r] = (r < BN) ? labels[r] : (r < MM ? r - BN : -1);
}

// ---- kernel C: per i-row, tot_i = sum_j e_ij (j!=i), pos_i = same over label match
// e_ij = exp2((cos_ij - 1) * (0.5/TEMP) * log2e)   [global-max shift cancels in ratio]
// Padded j-columns (rn==0) contribute exactly exp2f(-K2) each to tot; the loss
// kernel subtracts the exact constant 9*exp2f(-K2). Padded labp=-1 never matches.
// 4 waves/block, each wave owns j-chunk = blockIdx.y*4 + wid (64 chunks total).
// NOTE: launch_bounds min-waves MUST stay <=2 — (256,5) forced VGPR=48 and
// spilled afrag to scratch (FETCH 410MB, 3x slowdown). Kernel needs ~160 VGPR.
__global__ __launch_bounds__(256, 2)
void main_kernel(const __hip_bfloat16* __restrict__ rn,
                 const int* __restrict__ labp,
                 float* __restrict__ tot,
                 float* __restrict__ pos) {
  __shared__ float red[128];   // [0..63]=tot for i-rows, [64..127]=pos
  const int lane = threadIdx.x & 63;
  const int wid  = threadIdx.x >> 6;
  const int q = lane >> 4, col = lane & 15;
  const int ibase = blockIdx.x * 64;
  const int chunk = (blockIdx.y << 2) | wid;   // 0..63
  const short* rns = (const short*)rn;

  if (threadIdx.x < 128) red[threadIdx.x] = 0.f;

  // A fragments: lane holds A[m=col][k = kk*32 + q*8 + 0..7]
  short8 afrag[4][4];
#pragma unroll
  for (int it = 0; it < 4; ++it) {
    const short8* p = (const short8*)(rns + (size_t)(ibase + it * 16 + col) * HH + q * 8);
    afrag[it][0] = p[0];
    afrag[it][1] = p[4];
    afrag[it][2] = p[8];
    afrag[it][3] = p[12];
  }
  // i-labels for C/D layout rows: row = q*4 + r
  int labi[4][4];
#pragma unroll
  for (int it = 0; it < 4; ++it)
#pragma unroll
    for (int r = 0; r < 4; ++r)
      labi[it][r] = labp[ibase + it * 16 + q * 4 + r];

  float stot[4][4] = {};
  float spos[4][4] = {};
  const float K2 = 10.30496147f;  // 0.5/0.07 * log2(e)

  // pointer-increment B addressing: chunk strides 64 tiles = 1024 rows
  const short* bptr = rns + (chunk * 16 + col) * HH + q * 8;
  const int* lptr = labp + chunk * 16 + col;

  for (int jb = chunk * 16; jb < MP; jb += 16 * JCHUNKS) {
    // B fragments: lane holds B[k = kk*32 + q*8 + 0..7][n=col] = rn[jb+col][k]
    short8 b0 = ((const short8*)bptr)[0];
    short8 b1 = ((const short8*)bptr)[4];
    short8 b2 = ((const short8*)bptr)[8];
    short8 b3 = ((const short8*)bptr)[12];
    const int labj = *lptr;
    bptr += 16 * JCHUNKS * HH;
    lptr += 16 * JCHUNKS;
#pragma unroll
    for (int it = 0; it < 4; ++it) {
      floatx4 acc = {0.f, 0.f, 0.f, 0.f};
      acc = __builtin_amdgcn_mfma_f32_16x16x32_bf16(afrag[it][0], b0, acc, 0, 0, 0);
      acc = __builtin_amdgcn_mfma_f32_16x16x32_bf16(afrag[it][1], b1, acc, 0, 0, 0);
      acc = __builtin_amdgcn_mfma_f32_16x16x32_bf16(afrag[it][2], b2, acc, 0, 0, 0);
      acc = __builtin_amdgcn_mfma_f32_16x16x32_bf16(afrag[it][3], b3, acc, 0, 0, 0);
      const bool isdiag = (jb == ibase + it * 16);  // wave-uniform
#pragma unroll
      for (int r = 0; r < 4; ++r) {
        // C/D layout: row = q*4 + r, col = lane&15 → i = ibase+it*16+q*4+r, j = jb+col
        float e = exp2f(fmaf(acc[r], K2, -K2));
        if (isdiag && (col == q * 4 + r)) e = 0.f;   // exclude diagonal j==i
        stot[it][r] += e;
        spos[it][r] += (labj == labi[it][r]) ? e : 0.f;
      }
    }
  }

  __syncthreads();   // red[] init visible (also orders with the loop above)

  // reduce across the 16 column-lanes (xor over low 4 lane bits), then across
  // the 4 waves of the block via LDS, then ONE global atomic per i-row.
#pragma unroll
  for (int it = 0; it < 4; ++it)
#pragma unroll
    for (int r = 0; r < 4; ++r) {
      float tt = stot[it][r], pp = spos[it][r];
#pragma unroll
      for (int m = 1; m <= 8; m <<= 1) {
        tt += __shfl_xor(tt, m);
        pp += __shfl_xor(pp, m);
      }
      if (col == 0) {
        int li = it * 16 + q * 4 + r;   // 0..63 local i-row
        atomicAdd(&red[li], tt);
        atomicAdd(&red[64 + li], pp);
      }
    }
  __syncthreads();
  if (threadIdx.x < 64)       atomicAdd(&tot[ibase + threadIdx.x], red[threadIdx.x]);
  else if (threadIdx.x < 128) atomicAdd(&pos[ibase + threadIdx.x - 64], red[threadIdx.x]);
}

// ---- kernel D: loss = sum(lv * (lv>0.3)) / (sum(lv>0.3) + eps),
//      lv = -log( ((pos/(tot-9*epad))/(hist[lab]+eps)) + eps )
__global__ __launch_bounds__(1024)
void loss_kernel(const float* __restrict__ tot,
                 const float* __restrict__ pos,
                 const int* __restrict__ labels,
                 float* __restrict__ out) {
  __shared__ int hist[NUM_HIST];
  __shared__ float s1[16], s2[16];
  const int tid = threadIdx.x;
  const int lane = tid & 63, wid = tid >> 6;
  if (tid < NUM_HIST) hist[tid] = 0;
  __syncthreads();
  // ballot-based histogram: 7 ballots per 1024-element stripe, no LDS contention
  int cnt0 = 0, cnt1 = 0, cnt2 = 0, cnt3 = 0, cnt4 = 0, cnt5 = 0, cnt6 = 0;
  for (int i = tid; i < BN; i += 1024) {
    int lab = labels[i];
    unsigned long long m0 = __ballot(lab == 0);
    unsigned long long m1 = __ballot(lab == 1);
    unsigned long long m2 = __ballot(lab == 2);
    unsigned long long m3 = __ballot(lab == 3);
    unsigned long long m4 = __ballot(lab == 4);
    unsigned long long m5 = __ballot(lab == 5);
    unsigned long long m6 = __ballot(lab == 6);
    if (lane == 0) {
      cnt0 += __popcll(m0); cnt1 += __popcll(m1); cnt2 += __popcll(m2);
      cnt3 += __popcll(m3); cnt4 += __popcll(m4); cnt5 += __popcll(m5);
      cnt6 += __popcll(m6);
    }
  }
  if (lane == 0) {
    atomicAdd(&hist[0], cnt0); atomicAdd(&hist[1], cnt1);
    atomicAdd(&hist[2], cnt2); atomicAdd(&hist[3], cnt3);
    atomicAdd(&hist[4], cnt4); atomicAdd(&hist[5], cnt5);
    atomicAdd(&hist[6], cnt6);
  }
  __syncthreads();
  const float K2 = 10.30496147f;
  const float epad = exp2f(-K2);     // exact value each padded column added to tot
  float lsum = 0.f, msum = 0.f;
  for (int i = tid; i < BN; i += 1024) {
    float t = tot[i] - 9.0f * epad;
    float p = pos[i];
    float c = (float)hist[labels[i]];   // = sum(pos_mask*mask) exactly
    float pr = (p / t) / (c + 1e-8f);
    float lv = -logf(pr + 1e-8f);
    if (lv > 0.3f) { lsum += lv; msum += 1.f; }
  }
#pragma unroll
  for (int m = 1; m < 64; m <<= 1) {
    lsum += __shfl_xor(lsum, m);
    msum += __shfl_xor(msum, m);
  }
  if (lane == 0) { s1[wid] = lsum; s2[wid] = msum; }
  __syncthreads();
  if (wid == 0) {
    float a = (lane < 16) ? s1[lane] : 0.f;
    float b = (lane < 16) ? s2[lane] : 0.f;
#pragma unroll
    for (int m = 1; m < 16; m <<= 1) {
      a += __shfl_xor(a, m);
      b += __shfl_xor(b, m);
    }
    if (lane == 0) out[0] = a / (b + 1e-8f);
  }
}

extern "C" void kernel_launch(void* const* d_in, const int* in_sizes, int n_in,
                              void* d_out, int out_size, void* d_ws, size_t ws_size,
                              hipStream_t stream) {
  const float* reps    = (const float*)d_in[0];  // [8192,128]
  const int*   labels  = (const int*)d_in[1];    // [8192]
  const float* centers = (const float*)d_in[2];  // [7,256]
  const float* fc_w    = (const float*)d_in[3];  // [128,256]
  const float* fc_b    = (const float*)d_in[4];  // [128]
  float* out = (float*)d_out;

  char* ws = (char*)d_ws;
  float* curr = (float*)ws;                              // 7*128*4   = 3584 B
  int* labp   = (int*)(ws + 4096);                       // 8208*4    = 32832 B
  __hip_bfloat16* rn = (__hip_bfloat16*)(ws + 40960);    // 8208*128*2 = 2101248 B
  float* tot = (float*)(ws + 40960 + 2101248);           // 8192*4
  float* pos = tot + BN;                                 // 8192*4

  hipMemsetAsync(tot, 0, 2 * BN * sizeof(float), stream);
  centers_kernel<<<224, 256, 0, stream>>>(centers, fc_w, fc_b, curr);
  norm_kernel<<<2052, 256, 0, stream>>>(reps, curr, labels, rn, labp);
  main_kernel<<<dim3(128, 16), 256, 0, stream>>>(rn, labp, tot, pos);
  loss_kernel<<<1, 1024, 0, stream>>>(tot, pos, labels, out);
}